// Round 1
// baseline (877.321 us; speedup 1.0000x reference)
//
#include <hip/hip_runtime.h>
#include <hip/hip_bf16.h>
#include <cstdint>

// Sparse top-2 MoE (DBRX experts), MI355X gfx950.
// Pipeline: router -> scan -> assign -> gemm1(silu-glu fused, dual B) -> gemm2(gated) -> combine.
// All GEMMs are B^T form (A[M,K] x B[N,K]) with mfma_f32_16x16x32_bf16, fp32 accum.

#define T_TOK 4096
#define DHID  2048
#define NEXP  8
#define IDIM  4096
#define NSLOT (T_TOK * 2)

#define BM 128
#define BN 128
#define BK 64

typedef __bf16 bf16x8 __attribute__((ext_vector_type(8)));
typedef float  f32x4  __attribute__((ext_vector_type(4)));

// ---------------- router: logits, top-2 gates, x -> bf16 ----------------
__global__ __launch_bounds__(64) void router_kernel(
    const float* __restrict__ x, const float* __restrict__ wr,
    __bf16* __restrict__ xb, int* __restrict__ topi, float* __restrict__ topg,
    int* __restrict__ cnt)
{
    int t = blockIdx.x;
    int lane = threadIdx.x;
    const float* xr = x + (size_t)t * DHID;
    float acc[NEXP];
#pragma unroll
    for (int e = 0; e < NEXP; ++e) acc[e] = 0.f;
    for (int j = 0; j < DHID / 64; ++j) {
        int d = lane + j * 64;
        float xv = xr[d];
        xb[(size_t)t * DHID + d] = (__bf16)xv;
#pragma unroll
        for (int e = 0; e < NEXP; ++e) acc[e] += xv * wr[e * DHID + d];
    }
#pragma unroll
    for (int e = 0; e < NEXP; ++e) {
#pragma unroll
        for (int s = 32; s > 0; s >>= 1) acc[e] += __shfl_xor(acc[e], s);
    }
    if (lane == 0) {
        int e0 = 0; float l0 = acc[0];
#pragma unroll
        for (int e = 1; e < NEXP; ++e) if (acc[e] > l0) { l0 = acc[e]; e0 = e; }
        int e1 = -1; float l1 = -3.4e38f;
#pragma unroll
        for (int e = 0; e < NEXP; ++e) if (e != e0 && acc[e] > l1) { l1 = acc[e]; e1 = e; }
        // softmax-top2-renorm == softmax over the two top logits
        float g0 = 1.f / (1.f + __expf(l1 - l0));
        topi[t * 2]     = e0; topi[t * 2 + 1] = e1;
        topg[t * 2]     = g0; topg[t * 2 + 1] = 1.f - g0;
        atomicAdd(&cnt[e0], 1); atomicAdd(&cnt[e1], 1);
    }
}

__global__ void scan_kernel(const int* __restrict__ cnt, int* __restrict__ basep,
                            int* __restrict__ fill)
{
    if (threadIdx.x == 0 && blockIdx.x == 0) {
        int s = 0;
#pragma unroll
        for (int e = 0; e < NEXP; ++e) { basep[e] = s; s += cnt[e]; fill[e] = 0; }
    }
}

__global__ __launch_bounds__(256) void assign_kernel(
    const int* __restrict__ topi, const float* __restrict__ topg,
    const int* __restrict__ basep, int* __restrict__ fill,
    int* __restrict__ tok_of_slot, float* __restrict__ gate_of_slot,
    int* __restrict__ slot_of)
{
    int t = blockIdx.x * 256 + threadIdx.x;
    if (t >= T_TOK) return;
#pragma unroll
    for (int k = 0; k < 2; ++k) {
        int e = topi[t * 2 + k];
        int slot = basep[e] + atomicAdd(&fill[e], 1);
        tok_of_slot[slot] = t;
        gate_of_slot[slot] = topg[t * 2 + k];
        slot_of[t * 2 + k] = slot;
    }
}

// ---------------- GEMM1: H = silu(X w1^T) * (X v1^T), per expert ----------------
__global__ __launch_bounds__(256, 2) void gemm1_kernel(
    const __bf16* __restrict__ xb, const float* __restrict__ w1,
    const float* __restrict__ v1, const int* __restrict__ tok_of_slot,
    const int* __restrict__ cnt, const int* __restrict__ basep,
    __bf16* __restrict__ H)
{
    int e  = blockIdx.z;
    int ne = cnt[e];
    int m0 = blockIdx.y * BM;
    if (m0 >= ne) return;
    int n0 = blockIdx.x * BN;
    int sbase = basep[e] + m0;

    __shared__ __bf16 As[BM * BK];
    __shared__ __bf16 B1s[BN * BK];
    __shared__ __bf16 B2s[BN * BK];
    __shared__ int toks[BM];

    int tid = threadIdx.x;
    if (tid < BM) {
        int t = 0;
        if (m0 + tid < ne) t = tok_of_slot[sbase + tid];
        toks[tid] = t;
    }
    __syncthreads();

    const float* w1e = w1 + (size_t)e * IDIM * DHID;
    const float* v1e = v1 + (size_t)e * IDIM * DHID;

    int lane = tid & 63;
    int wave = tid >> 6;
    int wr0 = (wave >> 1) * 64;
    int wc0 = (wave & 1) * 64;

    f32x4 acc1[4][4], acc2[4][4];
    f32x4 zf = {0.f, 0.f, 0.f, 0.f};
#pragma unroll
    for (int m = 0; m < 4; ++m)
#pragma unroll
        for (int n = 0; n < 4; ++n) { acc1[m][n] = zf; acc2[m][n] = zf; }

    char* AsB = (char*)As;
    char* B1B = (char*)B1s;
    char* B2B = (char*)B2s;

    // hoisted per-thread staging constants (row0..row0+96, fixed ch)
    int row0 = tid >> 3;
    int ch   = tid & 7;
    int g    = row0 & 7;                 // (row0+32p)&7 == row0&7
    const __bf16* a_src[4];
    const float*  b1_src[4];
    const float*  b2_src[4];
    int dstoff[4];
#pragma unroll
    for (int p = 0; p < 4; ++p) {
        int row = row0 + 32 * p;
        a_src[p]  = xb  + (size_t)toks[row] * DHID + ch * 8;
        b1_src[p] = w1e + (size_t)(n0 + row) * DHID + ch * 8;
        b2_src[p] = v1e + (size_t)(n0 + row) * DHID + ch * 8;
        dstoff[p] = row * 128 + ((ch * 16) ^ (g << 4));   // XOR bank swizzle
    }

    for (int k0 = 0; k0 < DHID; k0 += BK) {
#pragma unroll
        for (int p = 0; p < 4; ++p)
            *(uint4*)(AsB + dstoff[p]) = *(const uint4*)(a_src[p] + k0);
#pragma unroll
        for (int p = 0; p < 4; ++p) {
            float4 fa = *(const float4*)(b1_src[p] + k0);
            float4 fb = *(const float4*)(b1_src[p] + k0 + 4);
            bf16x8 bv;
            bv[0]=(__bf16)fa.x; bv[1]=(__bf16)fa.y; bv[2]=(__bf16)fa.z; bv[3]=(__bf16)fa.w;
            bv[4]=(__bf16)fb.x; bv[5]=(__bf16)fb.y; bv[6]=(__bf16)fb.z; bv[7]=(__bf16)fb.w;
            *(bf16x8*)(B1B + dstoff[p]) = bv;
        }
#pragma unroll
        for (int p = 0; p < 4; ++p) {
            float4 fa = *(const float4*)(b2_src[p] + k0);
            float4 fb = *(const float4*)(b2_src[p] + k0 + 4);
            bf16x8 bv;
            bv[0]=(__bf16)fa.x; bv[1]=(__bf16)fa.y; bv[2]=(__bf16)fa.z; bv[3]=(__bf16)fa.w;
            bv[4]=(__bf16)fb.x; bv[5]=(__bf16)fb.y; bv[6]=(__bf16)fb.z; bv[7]=(__bf16)fb.w;
            *(bf16x8*)(B2B + dstoff[p]) = bv;
        }
        __syncthreads();
#pragma unroll
        for (int ks = 0; ks < 2; ++ks) {
            int kb = ks * 64 + (lane >> 4) * 16;
            bf16x8 af[4], b1f[4], b2f[4];
#pragma unroll
            for (int m = 0; m < 4; ++m) {
                int row = wr0 + m * 16 + (lane & 15);
                af[m] = *(const bf16x8*)(AsB + row * 128 + (kb ^ ((row & 7) << 4)));
            }
#pragma unroll
            for (int n = 0; n < 4; ++n) {
                int row = wc0 + n * 16 + (lane & 15);
                int off = row * 128 + (kb ^ ((row & 7) << 4));
                b1f[n] = *(const bf16x8*)(B1B + off);
                b2f[n] = *(const bf16x8*)(B2B + off);
            }
#pragma unroll
            for (int m = 0; m < 4; ++m)
#pragma unroll
                for (int n = 0; n < 4; ++n) {
                    acc1[m][n] = __builtin_amdgcn_mfma_f32_16x16x32_bf16(af[m], b1f[n], acc1[m][n], 0, 0, 0);
                    acc2[m][n] = __builtin_amdgcn_mfma_f32_16x16x32_bf16(af[m], b2f[n], acc2[m][n], 0, 0, 0);
                }
        }
        __syncthreads();
    }

    // epilogue: h = silu(acc1) * acc2 -> bf16 H[slot][n]
#pragma unroll
    for (int m = 0; m < 4; ++m) {
        int rbase = wr0 + m * 16 + ((lane >> 4) * 4);
#pragma unroll
        for (int n = 0; n < 4; ++n) {
            int col = n0 + wc0 + n * 16 + (lane & 15);
#pragma unroll
            for (int r = 0; r < 4; ++r) {
                int lrow = rbase + r;
                if (m0 + lrow < ne) {
                    float a = acc1[m][n][r];
                    float b = acc2[m][n][r];
                    float h = (a / (1.f + __expf(-a))) * b;
                    H[(size_t)(sbase + lrow) * IDIM + col] = (__bf16)h;
                }
            }
        }
    }
}

// ---------------- GEMM2: outslot = gate * (H w2^T), per expert ----------------
__global__ __launch_bounds__(256, 2) void gemm2_kernel(
    const __bf16* __restrict__ H, const float* __restrict__ w2,
    const float* __restrict__ gate_of_slot, const int* __restrict__ cnt,
    const int* __restrict__ basep, __bf16* __restrict__ outslot)
{
    int e  = blockIdx.z;
    int ne = cnt[e];
    int m0 = blockIdx.y * BM;
    if (m0 >= ne) return;
    int n0 = blockIdx.x * BN;
    int sbase = basep[e] + m0;

    __shared__ __bf16 As[BM * BK];
    __shared__ __bf16 Bs[BN * BK];
    __shared__ float gates[BM];

    int tid = threadIdx.x;
    if (tid < BM) {
        int srow = sbase + tid;
        if (m0 + tid >= ne) srow = sbase;
        gates[tid] = gate_of_slot[srow];
    }

    const float* w2e = w2 + (size_t)e * DHID * IDIM;

    int lane = tid & 63;
    int wave = tid >> 6;
    int wr0 = (wave >> 1) * 64;
    int wc0 = (wave & 1) * 64;

    f32x4 acc[4][4];
    f32x4 zf = {0.f, 0.f, 0.f, 0.f};
#pragma unroll
    for (int m = 0; m < 4; ++m)
#pragma unroll
        for (int n = 0; n < 4; ++n) acc[m][n] = zf;

    char* AsB = (char*)As;
    char* BsB = (char*)Bs;

    int row0 = tid >> 3;
    int ch   = tid & 7;
    int g    = row0 & 7;
    const __bf16* a_src[4];
    const float*  b_src[4];
    int dstoff[4];
#pragma unroll
    for (int p = 0; p < 4; ++p) {
        int row = row0 + 32 * p;
        int srow = sbase + row;
        if (m0 + row >= ne) srow = sbase;                 // clamp OOB rows
        a_src[p]  = H   + (size_t)srow * IDIM + ch * 8;
        b_src[p]  = w2e + (size_t)(n0 + row) * IDIM + ch * 8;
        dstoff[p] = row * 128 + ((ch * 16) ^ (g << 4));
    }

    for (int k0 = 0; k0 < IDIM; k0 += BK) {
#pragma unroll
        for (int p = 0; p < 4; ++p)
            *(uint4*)(AsB + dstoff[p]) = *(const uint4*)(a_src[p] + k0);
#pragma unroll
        for (int p = 0; p < 4; ++p) {
            float4 fa = *(const float4*)(b_src[p] + k0);
            float4 fb = *(const float4*)(b_src[p] + k0 + 4);
            bf16x8 bv;
            bv[0]=(__bf16)fa.x; bv[1]=(__bf16)fa.y; bv[2]=(__bf16)fa.z; bv[3]=(__bf16)fa.w;
            bv[4]=(__bf16)fb.x; bv[5]=(__bf16)fb.y; bv[6]=(__bf16)fb.z; bv[7]=(__bf16)fb.w;
            *(bf16x8*)(BsB + dstoff[p]) = bv;
        }
        __syncthreads();
#pragma unroll
        for (int ks = 0; ks < 2; ++ks) {
            int kb = ks * 64 + (lane >> 4) * 16;
            bf16x8 af[4], bf[4];
#pragma unroll
            for (int m = 0; m < 4; ++m) {
                int row = wr0 + m * 16 + (lane & 15);
                af[m] = *(const bf16x8*)(AsB + row * 128 + (kb ^ ((row & 7) << 4)));
            }
#pragma unroll
            for (int n = 0; n < 4; ++n) {
                int row = wc0 + n * 16 + (lane & 15);
                bf[n] = *(const bf16x8*)(BsB + row * 128 + (kb ^ ((row & 7) << 4)));
            }
#pragma unroll
            for (int m = 0; m < 4; ++m)
#pragma unroll
                for (int n = 0; n < 4; ++n)
                    acc[m][n] = __builtin_amdgcn_mfma_f32_16x16x32_bf16(af[m], bf[n], acc[m][n], 0, 0, 0);
        }
        __syncthreads();
    }

#pragma unroll
    for (int m = 0; m < 4; ++m) {
        int rbase = wr0 + m * 16 + ((lane >> 4) * 4);
#pragma unroll
        for (int n = 0; n < 4; ++n) {
            int col = n0 + wc0 + n * 16 + (lane & 15);
#pragma unroll
            for (int r = 0; r < 4; ++r) {
                int lrow = rbase + r;
                if (m0 + lrow < ne) {
                    float v = acc[m][n][r] * gates[lrow];
                    outslot[(size_t)(sbase + lrow) * DHID + col] = (__bf16)v;
                }
            }
        }
    }
}

// ---------------- combine: out[t] = outslot[s0] + outslot[s1] ----------------
__global__ __launch_bounds__(256) void combine_kernel(
    const __bf16* __restrict__ outslot, const int* __restrict__ slot_of,
    float* __restrict__ out)
{
    int idx = blockIdx.x * 256 + threadIdx.x;
    int t = idx >> 8;                 // DHID/8 = 256 chunks per token
    int c = (idx & 255) * 8;
    int s0 = slot_of[t * 2], s1 = slot_of[t * 2 + 1];
    bf16x8 a = *(const bf16x8*)(outslot + (size_t)s0 * DHID + c);
    bf16x8 b = *(const bf16x8*)(outslot + (size_t)s1 * DHID + c);
    float4 o0, o1;
    o0.x = (float)a[0] + (float)b[0];
    o0.y = (float)a[1] + (float)b[1];
    o0.z = (float)a[2] + (float)b[2];
    o0.w = (float)a[3] + (float)b[3];
    o1.x = (float)a[4] + (float)b[4];
    o1.y = (float)a[5] + (float)b[5];
    o1.z = (float)a[6] + (float)b[6];
    o1.w = (float)a[7] + (float)b[7];
    *(float4*)(out + (size_t)t * DHID + c)     = o0;
    *(float4*)(out + (size_t)t * DHID + c + 4) = o1;
}

extern "C" void kernel_launch(void* const* d_in, const int* in_sizes, int n_in,
                              void* d_out, int out_size, void* d_ws, size_t ws_size,
                              hipStream_t stream)
{
    (void)in_sizes; (void)n_in; (void)out_size; (void)ws_size;
    const float* x  = (const float*)d_in[0];
    const float* wr = (const float*)d_in[1];
    const float* w1 = (const float*)d_in[2];
    const float* v1 = (const float*)d_in[3];
    const float* w2 = (const float*)d_in[4];
    float* out = (float*)d_out;

    char* ws = (char*)d_ws;
    size_t off = 0;
    auto alloc = [&](size_t bytes) -> void* {
        void* p = ws + off;
        off += bytes;
        off = (off + 255) & ~(size_t)255;
        return p;
    };
    __bf16* xb       = (__bf16*)alloc((size_t)T_TOK * DHID * 2);
    __bf16* H        = (__bf16*)alloc((size_t)NSLOT * IDIM * 2);
    __bf16* outslot  = (__bf16*)alloc((size_t)NSLOT * DHID * 2);
    int*    topi     = (int*)  alloc((size_t)T_TOK * 2 * 4);
    float*  topg     = (float*)alloc((size_t)T_TOK * 2 * 4);
    int*    tok_of_slot  = (int*)  alloc((size_t)NSLOT * 4);
    float*  gate_of_slot = (float*)alloc((size_t)NSLOT * 4);
    int*    slot_of  = (int*)  alloc((size_t)NSLOT * 4);
    int*    cnt      = (int*)  alloc(NEXP * 4);
    int*    basep    = (int*)  alloc(NEXP * 4);
    int*    fill     = (int*)  alloc(NEXP * 4);

    hipMemsetAsync(cnt, 0, NEXP * 4, stream);
    router_kernel<<<T_TOK, 64, 0, stream>>>(x, wr, xb, topi, topg, cnt);
    scan_kernel<<<1, 64, 0, stream>>>(cnt, basep, fill);
    assign_kernel<<<T_TOK / 256, 256, 0, stream>>>(topi, topg, basep, fill,
                                                   tok_of_slot, gate_of_slot, slot_of);
    gemm1_kernel<<<dim3(IDIM / BN, T_TOK / BM, NEXP), 256, 0, stream>>>(
        xb, w1, v1, tok_of_slot, cnt, basep, H);
    gemm2_kernel<<<dim3(DHID / BN, T_TOK / BM, NEXP), 256, 0, stream>>>(
        H, w2, gate_of_slot, cnt, basep, outslot);
    combine_kernel<<<(T_TOK * DHID / 8) / 256, 256, 0, stream>>>(outslot, slot_of, out);
}